// Round 4
// baseline (375.184 us; speedup 1.0000x reference)
//
#include <hip/hip_runtime.h>

using short8 = __attribute__((ext_vector_type(8))) short;          // 8 bf16 (4 VGPR)
using short4v = __attribute__((ext_vector_type(4))) short;         // 4 bf16 (8B)
using f32x4  = __attribute__((ext_vector_type(4))) float;          // MFMA acc
using u16x4  = __attribute__((ext_vector_type(4))) unsigned short; // 8B bf16 store

#define AS1 __attribute__((address_space(1)))
#define AS3 __attribute__((address_space(3)))

__device__ __forceinline__ unsigned short f2bf(float f) {
    unsigned u = __builtin_bit_cast(unsigned, f);
    u += 0x7fffu + ((u >> 16) & 1u);           // RNE
    return (unsigned short)(u >> 16);
}

// ---------------------------------------------------------------- LN -> bf16
__global__ __launch_bounds__(256) void ln_to_bf16(
    const float* __restrict__ X, const float* __restrict__ gw,
    const float* __restrict__ bw, unsigned short* __restrict__ Y)
{
    const int row = blockIdx.x;
    const int tid = threadIdx.x;
    const float4 v = *(const float4*)(X + (size_t)row * 1024 + tid * 4);
    float s  = v.x + v.y + v.z + v.w;
    float s2 = v.x*v.x + v.y*v.y + v.z*v.z + v.w*v.w;
    #pragma unroll
    for (int off = 1; off < 64; off <<= 1) {
        s  += __shfl_xor(s,  off);
        s2 += __shfl_xor(s2, off);
    }
    __shared__ float rs[4], rq[4];
    if ((tid & 63) == 0) { rs[tid >> 6] = s; rq[tid >> 6] = s2; }
    __syncthreads();
    s  = rs[0] + rs[1] + rs[2] + rs[3];
    s2 = rq[0] + rq[1] + rq[2] + rq[3];
    const float mean = s * (1.f / 1024.f);
    const float var  = s2 * (1.f / 1024.f) - mean * mean;
    const float rstd = rsqrtf(var + 1e-5f);
    const float4 gv = *(const float4*)(gw + tid * 4);
    const float4 bv = *(const float4*)(bw + tid * 4);
    u16x4 o;
    o[0] = f2bf((v.x - mean) * rstd * gv.x + bv.x);
    o[1] = f2bf((v.y - mean) * rstd * gv.y + bv.y);
    o[2] = f2bf((v.z - mean) * rstd * gv.z + bv.z);
    o[3] = f2bf((v.w - mean) * rstd * gv.w + bv.w);
    *(u16x4*)(Y + (size_t)row * 1024 + tid * 4) = o;
}

// ---------------------------------------------------------------- f32 -> bf16
__global__ __launch_bounds__(256) void cast_bf16(
    const float* __restrict__ X, unsigned short* __restrict__ Y, int n4)
{
    int i = blockIdx.x * 256 + threadIdx.x;
    if (i >= n4) return;
    float4 v = ((const float4*)X)[i];
    u16x4 o = { f2bf(v.x), f2bf(v.y), f2bf(v.z), f2bf(v.w) };
    ((u16x4*)Y)[i] = o;
}

// ------------------------------------------------- W[K][N] f32 -> Wt[N][K] bf16
__global__ __launch_bounds__(256) void transpose_cast(
    const float* __restrict__ W, unsigned short* __restrict__ Wt, int K, int N)
{
    __shared__ float t[32][33];
    const int kb = blockIdx.x % (K >> 5);
    const int nb = blockIdx.x / (K >> 5);
    const int c = threadIdx.x & 31, r0 = threadIdx.x >> 5;
    #pragma unroll
    for (int i = 0; i < 4; i++)
        t[r0 + i * 8][c] = W[(size_t)(kb * 32 + r0 + i * 8) * N + nb * 32 + c];
    __syncthreads();
    #pragma unroll
    for (int i = 0; i < 4; i++)
        Wt[(size_t)(nb * 32 + r0 + i * 8) * K + kb * 32 + c] = f2bf(t[c][r0 + i * 8]);
}

// ---------------------------- four fused 1024x1024 transposes (one launch)
__global__ __launch_bounds__(256) void transpose_cast4(
    const float* __restrict__ w0, const float* __restrict__ w1,
    const float* __restrict__ w2, const float* __restrict__ w3,
    unsigned short* __restrict__ t0, unsigned short* __restrict__ t1,
    unsigned short* __restrict__ t2, unsigned short* __restrict__ t3)
{
    __shared__ float t[32][33];
    const int which = blockIdx.x >> 10;
    const float* W = which == 0 ? w0 : which == 1 ? w1 : which == 2 ? w2 : w3;
    unsigned short* Wt = which == 0 ? t0 : which == 1 ? t1 : which == 2 ? t2 : t3;
    const int idx = blockIdx.x & 1023;
    const int kb = idx & 31, nb = idx >> 5;
    const int c = threadIdx.x & 31, r0 = threadIdx.x >> 5;
    #pragma unroll
    for (int i = 0; i < 4; i++)
        t[r0 + i * 8][c] = W[(size_t)(kb * 32 + r0 + i * 8) * 1024 + nb * 32 + c];
    __syncthreads();
    #pragma unroll
    for (int i = 0; i < 4; i++)
        Wt[(size_t)(nb * 32 + r0 + i * 8) * 1024 + kb * 32 + c] = f2bf(t[c][r0 + i * 8]);
}

// --------------------------------------------- GEMM (m97 + T3 min-2-phase dbuf)
// C[m][n] = sum_k A[m][k] * Bt[n][k] + bias[n], BM=128 x BN tile, BK=32, 4 waves.
// EPI: 0 = bf16 out; 1 = V-transposed bf16 ([B*H][64][1024]); 2 = relu bf16;
//      3 = f32 out = resid + C; 4 = fused KV (col<1024 -> Kb linear, else Vt transposed)
template<int EPI, int BN>
__global__ __launch_bounds__(256) void gemm_bt(
    const unsigned short* __restrict__ A, const unsigned short* __restrict__ Bt,
    const float* __restrict__ bias, const float* __restrict__ bias2,
    void* __restrict__ outp, void* __restrict__ outp2,
    const float* __restrict__ resid, int M, int N, int K)
{
    constexpr int NF = BN / 32;                 // frags per wave in N
    constexpr int LDSH = (128 + BN) * 32;       // elems per buffer (A then B)
    __shared__ unsigned short S[2 * LDSH];      // double buffer
    const int tid = threadIdx.x;
    const int lane = tid & 63, wave = tid >> 6;
    const int g = lane >> 4, q16 = lane & 15;
    const int wm = wave >> 1, wn = wave & 1;
    const int nb = N / BN;
    const int bm = blockIdx.x / nb, bn = blockIdx.x % nb;

    const unsigned short* aSrc = A  + (size_t)(bm * 128 + (tid >> 2)) * K + (tid & 3) * 8;
    const unsigned short* bSrc = Bt + (size_t)(bn * BN  + (tid >> 2)) * K + (tid & 3) * 8;
    const size_t rowStep = (size_t)64 * K;

    f32x4 acc[4][NF] = {};

    auto STAGE = [&](int buf, int kt) {
        unsigned short* aDst = &S[buf * LDSH] + wave * 512;        // wave-uniform base
        unsigned short* bDst = &S[buf * LDSH + 4096] + wave * 512;
        __builtin_amdgcn_global_load_lds((const AS1 unsigned int*)(aSrc + kt),           (AS3 unsigned int*)aDst,          16, 0, 0);
        __builtin_amdgcn_global_load_lds((const AS1 unsigned int*)(aSrc + rowStep + kt), (AS3 unsigned int*)(aDst + 2048), 16, 0, 0);
        __builtin_amdgcn_global_load_lds((const AS1 unsigned int*)(bSrc + kt),           (AS3 unsigned int*)bDst,          16, 0, 0);
        if constexpr (BN == 128)
            __builtin_amdgcn_global_load_lds((const AS1 unsigned int*)(bSrc + rowStep + kt), (AS3 unsigned int*)(bDst + 2048), 16, 0, 0);
    };
    auto COMPUTE = [&](int buf) {
        const unsigned short* As = &S[buf * LDSH];
        const unsigned short* Bs = As + 4096;
        short8 af[4], bfr[NF];
        #pragma unroll
        for (int i = 0; i < 4; i++)  af[i]  = *(const short8*)(As + (wm * 64 + i * 16 + q16) * 32 + g * 8);
        #pragma unroll
        for (int i = 0; i < NF; i++) bfr[i] = *(const short8*)(Bs + (wn * (BN / 2) + i * 16 + q16) * 32 + g * 8);
        #pragma unroll
        for (int mf = 0; mf < 4; mf++)
            #pragma unroll
            for (int nf = 0; nf < NF; nf++)
                acc[mf][nf] = __builtin_amdgcn_mfma_f32_16x16x32_bf16(af[mf], bfr[nf], acc[mf][nf], 0, 0, 0);
    };

    STAGE(0, 0);
    __syncthreads();                 // drains vmcnt(0): buf0 ready
    int cur = 0;
    for (int kt = 32; kt < K; kt += 32) {
        STAGE(cur ^ 1, kt);          // prefetch flies under the MFMAs below
        COMPUTE(cur);
        __syncthreads();             // drain: next buf ready, cur free for overwrite
        cur ^= 1;
    }
    COMPUTE(cur);                    // last tile (no prefetch)

    const int row0 = bm * 128 + wm * 64;
    const int col0 = bn * BN + wn * (BN / 2);
    const bool isV = (EPI == 4) && (bn * BN >= 1024);   // KV-fusion: whole block uniform
    #pragma unroll
    for (int nf = 0; nf < NF; nf++) {
        const int col = col0 + nf * 16 + q16;
        const float bv = (EPI == 4 && isV) ? bias2[col - 1024] : bias[col];
        #pragma unroll
        for (int mf = 0; mf < 4; mf++) {
            const int rbase = row0 + mf * 16 + g * 4;
            #pragma unroll
            for (int r = 0; r < 4; r++) {
                const int row = rbase + r;
                const float v = acc[mf][nf][r] + bv;
                if constexpr (EPI == 0) {
                    ((unsigned short*)outp)[(size_t)row * N + col] = f2bf(v);
                } else if constexpr (EPI == 1) {
                    const int bI = row >> 10, lk = row & 1023, hh = col >> 6, dd = col & 63;
                    ((unsigned short*)outp)[((size_t)(bI * 16 + hh) * 64 + dd) * 1024 + lk] = f2bf(v);
                } else if constexpr (EPI == 2) {
                    ((unsigned short*)outp)[(size_t)row * N + col] = f2bf(v > 0.f ? v : 0.f);
                } else if constexpr (EPI == 3) {
                    ((float*)outp)[(size_t)row * N + col] = resid[(size_t)row * N + col] + v;
                } else {  // EPI == 4: fused K/V projection, N==2048
                    if (!isV) {
                        ((unsigned short*)outp)[(size_t)row * 1024 + col] = f2bf(v);
                    } else {
                        const int cc = col - 1024;
                        const int bI = row >> 10, lk = row & 1023, hh = cc >> 6, dd = cc & 63;
                        ((unsigned short*)outp2)[((size_t)(bI * 16 + hh) * 64 + dd) * 1024 + lk] = f2bf(v);
                    }
                }
            }
        }
    }
}

// ------------------------------------------------------------- attention PV
// Per block: one (b,h,128-q tile); per wave: 32 q rows, full k sweep.
// S^T = mfma(K,Q) leaves lane (g,q) holding keys pi(g,j) = {4g..4g+3, 16+4g..19+4g}.
// PV uses the SAME bijection pi for V's A-fragment (two short4 loads), so P
// stays in-lane: ZERO cross-lane shuffles. K/V register-prefetched 1 chunk deep.
__global__ __launch_bounds__(256) void att_pv(
    const unsigned short* __restrict__ Q, const unsigned short* __restrict__ Kb,
    const unsigned short* __restrict__ Vt, unsigned short* __restrict__ O,
    float* __restrict__ LINV)
{
    const int tid = threadIdx.x;
    const int lane = tid & 63, wave = tid >> 6;
    const int g = lane >> 4, q16 = lane & 15;
    const int qblk = blockIdx.x & 7;
    const int bh = blockIdx.x >> 3;
    const int b = bh >> 4, h = bh & 15;
    const int qbase = qblk * 128 + wave * 32;

    const unsigned short* Kp = Kb + (size_t)(b * 1024) * 1024 + h * 64;   // row stride 1024
    const unsigned short* Vp = Vt + (size_t)(bh * 64 + q16) * 1024;       // +mf*16 rows

    short8 qf[2][2];
    #pragma unroll
    for (int nf = 0; nf < 2; nf++)
        #pragma unroll
        for (int ds = 0; ds < 2; ds++)
            qf[nf][ds] = *(const short8*)(Q + (size_t)(b * 1024 + qbase + nf * 16 + q16) * 1024 + h * 64 + ds * 32 + g * 8);

    f32x4 oacc[4][2] = {};
    float lsum[2] = {0.f, 0.f};

    auto LOADK = [&](short8 (&kf)[2][2], int kc) {
        #pragma unroll
        for (int kt = 0; kt < 2; kt++)
            #pragma unroll
            for (int ds = 0; ds < 2; ds++)
                kf[kt][ds] = *(const short8*)(Kp + (size_t)(kc + kt * 16 + q16) * 1024 + ds * 32 + g * 8);
    };
    auto LOADV = [&](short8 (&vf)[4], int kc) {
        #pragma unroll
        for (int mf = 0; mf < 4; mf++) {
            const unsigned short* vp = Vp + (size_t)(mf * 16) * 1024 + kc + g * 4;
            short4v lo = *(const short4v*)(vp);        // keys kc+4g .. kc+4g+3
            short4v hi = *(const short4v*)(vp + 16);   // keys kc+16+4g .. kc+19+4g
            vf[mf] = short8{lo[0], lo[1], lo[2], lo[3], hi[0], hi[1], hi[2], hi[3]};
        }
    };
    auto BODY = [&](short8 (&kf)[2][2], short8 (&vf)[4]) {
        f32x4 sacc[2][2] = {};
        #pragma unroll
        for (int kt = 0; kt < 2; kt++)
            #pragma unroll
            for (int nf = 0; nf < 2; nf++) {
                sacc[kt][nf] = __builtin_amdgcn_mfma_f32_16x16x32_bf16(kf[kt][0], qf[nf][0], sacc[kt][nf], 0, 0, 0);
                sacc[kt][nf] = __builtin_amdgcn_mfma_f32_16x16x32_bf16(kf[kt][1], qf[nf][1], sacc[kt][nf], 0, 0, 0);
            }
        // lane (g,q16) holds S^T[key = kc + kt*16 + 4g + r][q = qbase + nf*16 + q16]
        float ps[2][2][4];
        #pragma unroll
        for (int kt = 0; kt < 2; kt++)
            #pragma unroll
            for (int nf = 0; nf < 2; nf++)
                #pragma unroll
                for (int r = 0; r < 4; r++)
                    ps[kt][nf][r] = __expf(sacc[kt][nf][r] * 0.125f);
        #pragma unroll
        for (int nf = 0; nf < 2; nf++) {
            float t = ps[0][nf][0] + ps[0][nf][1] + ps[0][nf][2] + ps[0][nf][3]
                    + ps[1][nf][0] + ps[1][nf][1] + ps[1][nf][2] + ps[1][nf][3];
            t += __shfl_xor(t, 16);
            t += __shfl_xor(t, 32);
            lsum[nf] += t;
        }
        // B-fragment slot j of lane (g,q): P^T[key = kc + pi(g,j)][q] — all in-lane.
        short8 pbf[2];
        #pragma unroll
        for (int nf = 0; nf < 2; nf++) {
            pbf[nf][0] = (short)f2bf(ps[0][nf][0]);
            pbf[nf][1] = (short)f2bf(ps[0][nf][1]);
            pbf[nf][2] = (short)f2bf(ps[0][nf][2]);
            pbf[nf][3] = (short)f2bf(ps[0][nf][3]);
            pbf[nf][4] = (short)f2bf(ps[1][nf][0]);
            pbf[nf][5] = (short)f2bf(ps[1][nf][1]);
            pbf[nf][6] = (short)f2bf(ps[1][nf][2]);
            pbf[nf][7] = (short)f2bf(ps[1][nf][3]);
        }
        #pragma unroll
        for (int mf = 0; mf < 4; mf++)
            #pragma unroll
            for (int nf = 0; nf < 2; nf++)
                oacc[mf][nf] = __builtin_amdgcn_mfma_f32_16x16x32_bf16(vf[mf], pbf[nf], oacc[mf][nf], 0, 0, 0);
    };

    short8 kfA[2][2], kfB[2][2], vfA[4], vfB[4];
    LOADK(kfA, 0); LOADV(vfA, 0);
    for (int kc = 0; kc < 1024; kc += 64) {
        LOADK(kfB, kc + 32); LOADV(vfB, kc + 32);   // prefetch flies under BODY(A)
        BODY(kfA, vfA);
        if (kc + 64 < 1024) { LOADK(kfA, kc + 64); LOADV(vfA, kc + 64); }
        BODY(kfB, vfB);
    }

    // normalize + write O (bf16 [4096][1024], col = h*64+d), stash 1/l
    #pragma unroll
    for (int nf = 0; nf < 2; nf++) {
        const float inv = 1.0f / lsum[nf];
        if (g == 0) LINV[(size_t)bh * 1024 + qbase + nf * 16 + q16] = inv;
        #pragma unroll
        for (int mf = 0; mf < 4; mf++) {
            u16x4 o;
            #pragma unroll
            for (int r = 0; r < 4; r++) o[r] = f2bf(oacc[mf][nf][r] * inv);
            *(u16x4*)(O + (size_t)(b * 1024 + qbase + nf * 16 + q16) * 1024 + h * 64 + mf * 16 + g * 4) = o;
        }
    }
}

// ------------------------------------------------- head-averaged attn output
// Block: (b, 64-q tile, 128-k tile); wave: 32 k. Loops all 16 heads,
// recomputes S with stored 1/l, accumulates mean prob, writes f32. grid=512.
__global__ __launch_bounds__(256) void att_mean(
    const unsigned short* __restrict__ Q, const unsigned short* __restrict__ Kb,
    const float* __restrict__ LINV, float* __restrict__ out1)
{
    const int tid = threadIdx.x;
    const int lane = tid & 63, wave = tid >> 6;
    const int g = lane >> 4, q16 = lane & 15;
    const int kb = blockIdx.x & 7;
    const int qb = (blockIdx.x >> 3) & 15;
    const int b = blockIdx.x >> 7;
    const int qbase = qb * 64;
    const int kbase = kb * 128 + wave * 32;

    f32x4 facc[4][2] = {};
    for (int h = 0; h < 16; h++) {
        short8 qf[4][2], kf[2][2];
        #pragma unroll
        for (int mf = 0; mf < 4; mf++)
            #pragma unroll
            for (int ds = 0; ds < 2; ds++)
                qf[mf][ds] = *(const short8*)(Q + (size_t)(b * 1024 + qbase + mf * 16 + q16) * 1024 + h * 64 + ds * 32 + g * 8);
        #pragma unroll
        for (int nf = 0; nf < 2; nf++)
            #pragma unroll
            for (int ds = 0; ds < 2; ds++)
                kf[nf][ds] = *(const short8*)(Kb + (size_t)(b * 1024 + kbase + nf * 16 + q16) * 1024 + h * 64 + ds * 32 + g * 8);
        const float* lp = LINV + (size_t)(b * 16 + h) * 1024 + qbase;
        float li[4][4];
        #pragma unroll
        for (int mf = 0; mf < 4; mf++)
            #pragma unroll
            for (int r = 0; r < 4; r++) li[mf][r] = lp[mf * 16 + g * 4 + r];
        #pragma unroll
        for (int nf = 0; nf < 2; nf++) {
            f32x4 sacc[4] = {};
            #pragma unroll
            for (int mf = 0; mf < 4; mf++) {
                sacc[mf] = __builtin_amdgcn_mfma_f32_16x16x32_bf16(qf[mf][0], kf[nf][0], sacc[mf], 0, 0, 0);
                sacc[mf] = __builtin_amdgcn_mfma_f32_16x16x32_bf16(qf[mf][1], kf[nf][1], sacc[mf], 0, 0, 0);
            }
            #pragma unroll
            for (int mf = 0; mf < 4; mf++)
                #pragma unroll
                for (int r = 0; r < 4; r++)
                    facc[mf][nf][r] += __expf(sacc[mf][r] * 0.125f) * li[mf][r];
        }
    }
    #pragma unroll
    for (int mf = 0; mf < 4; mf++)
        #pragma unroll
        for (int nf = 0; nf < 2; nf++)
            #pragma unroll
            for (int r = 0; r < 4; r++)
                out1[(size_t)(b * 1024 + qbase + mf * 16 + g * 4 + r) * 1024 + kbase + nf * 16 + q16]
                    = facc[mf][nf][r] * 0.0625f;
}

// ---------------------------------------------------------------- launcher
extern "C" void kernel_launch(void* const* d_in, const int* in_sizes, int n_in,
                              void* d_out, int out_size, void* d_ws, size_t ws_size,
                              hipStream_t stream)
{
    (void)in_sizes; (void)n_in; (void)out_size; (void)ws_size;
    const float* tgt  = (const float*)d_in[0];
    const float* mem  = (const float*)d_in[1];
    const float* ln1g = (const float*)d_in[2];
    const float* ln1b = (const float*)d_in[3];
    const float* wq   = (const float*)d_in[4];
    const float* bq   = (const float*)d_in[5];
    const float* wk   = (const float*)d_in[6];
    const float* bk   = (const float*)d_in[7];
    const float* wv   = (const float*)d_in[8];
    const float* bv   = (const float*)d_in[9];
    const float* wo   = (const float*)d_in[10];
    const float* bo   = (const float*)d_in[11];
    const float* ln3g = (const float*)d_in[12];
    const float* ln3b = (const float*)d_in[13];
    const float* w1   = (const float*)d_in[14];
    const float* b1   = (const float*)d_in[15];
    const float* w2   = (const float*)d_in[16];
    const float* b2   = (const float*)d_in[17];

    char* ws = (char*)d_ws;
    unsigned short* XA  = (unsigned short*)(ws);                  // 8 MB (t2, later t3)
    unsigned short* M16 = (unsigned short*)(ws + ((size_t)8  << 20));
    unsigned short* WQT = (unsigned short*)(ws + ((size_t)16 << 20));
    unsigned short* WKT = (unsigned short*)(ws + ((size_t)18 << 20)); // [WKT;WVT] = fused 2048xK
    unsigned short* WVT = (unsigned short*)(ws + ((size_t)20 << 20));
    unsigned short* WOT = (unsigned short*)(ws + ((size_t)22 << 20));
    unsigned short* W1T = (unsigned short*)(ws + ((size_t)24 << 20)); // 8 MB
    unsigned short* W2T = (unsigned short*)(ws + ((size_t)32 << 20)); // 8 MB
    unsigned short* Qb  = (unsigned short*)(ws + ((size_t)40 << 20));
    unsigned short* Kb  = (unsigned short*)(ws + ((size_t)48 << 20));
    unsigned short* Vt  = (unsigned short*)(ws + ((size_t)56 << 20));
    unsigned short* O16 = (unsigned short*)(ws + ((size_t)64 << 20));
    unsigned short* H16 = (unsigned short*)(ws + ((size_t)72 << 20)); // 32 MB
    float*          LNV = (float*)(ws + ((size_t)104 << 20));         // 256 KB
    float* xout = (float*)d_out;                       // x then x+ffn [4096][1024]
    float* attn = xout + (size_t)4 * 1024 * 1024;      // [4][1024][1024]

    ln_to_bf16<<<4096, 256, 0, stream>>>(tgt, ln1g, ln1b, XA);
    cast_bf16<<<4096, 256, 0, stream>>>(mem, M16, 1024 * 1024);
    transpose_cast4<<<4096, 256, 0, stream>>>(wq, wk, wv, wo, WQT, WKT, WVT, WOT);
    transpose_cast<<<32 * 128, 256, 0, stream>>>(w1, W1T, 1024, 4096);
    transpose_cast<<<128 * 32, 256, 0, stream>>>(w2, W2T, 4096, 1024);

    // Q projection: N=1024, BN=64 -> grid 512 (2 blocks/CU)
    gemm_bt<0, 64><<<32 * 16, 256, 0, stream>>>(XA, WQT, bq, nullptr, Qb, nullptr, nullptr, 4096, 1024, 1024);
    // fused K+V projection: N=2048, BN=128 -> grid 512
    gemm_bt<4, 128><<<32 * 16, 256, 0, stream>>>(M16, WKT, bk, bv, Kb, Vt, nullptr, 4096, 2048, 1024);

    att_pv<<<512, 256, 0, stream>>>(Qb, Kb, Vt, O16, LNV);
    att_mean<<<512, 256, 0, stream>>>(Qb, Kb, LNV, attn);

    // WO: N=1024, BN=64 -> grid 512
    gemm_bt<3, 64><<<32 * 16, 256, 0, stream>>>(O16, WOT, bo, nullptr, xout, nullptr, tgt, 4096, 1024, 1024);
    ln_to_bf16<<<4096, 256, 0, stream>>>(xout, ln3g, ln3b, XA);
    // FFN1: N=4096, BN=128 -> grid 1024
    gemm_bt<2, 128><<<32 * 32, 256, 0, stream>>>(XA, W1T, b1, nullptr, H16, nullptr, nullptr, 4096, 4096, 1024);
    // FFN2: N=1024, K=4096, BN=64 -> grid 512
    gemm_bt<3, 64><<<32 * 16, 256, 0, stream>>>(H16, W2T, b2, nullptr, xout, nullptr, xout, 4096, 1024, 4096);
}

// Round 5
// 350.161 us; speedup vs baseline: 1.0715x; 1.0715x over previous
//
#include <hip/hip_runtime.h>

using short8 = __attribute__((ext_vector_type(8))) short;          // 8 bf16 (4 VGPR)
using f32x4  = __attribute__((ext_vector_type(4))) float;          // MFMA acc
using u16x4  = __attribute__((ext_vector_type(4))) unsigned short; // 8B bf16 store

#define AS1 __attribute__((address_space(1)))
#define AS3 __attribute__((address_space(3)))

__device__ __forceinline__ unsigned short f2bf(float f) {
    unsigned u = __builtin_bit_cast(unsigned, f);
    u += 0x7fffu + ((u >> 16) & 1u);           // RNE
    return (unsigned short)(u >> 16);
}

// pi-permutation of key k within a 32-key chunk: position of key k in the
// slot order {4g..4g+3, 16+4g..19+4g} for g = 0..3 (slot = g*8+j).
__device__ __forceinline__ int vperm(int lk) {
    return (lk & ~31) | (((lk >> 2) & 3) * 8) | (((lk >> 4) & 1) * 4) | (lk & 3);
}

// ---------------------------------------------------------------- LN -> bf16
__global__ __launch_bounds__(256) void ln_to_bf16(
    const float* __restrict__ X, const float* __restrict__ gw,
    const float* __restrict__ bw, unsigned short* __restrict__ Y)
{
    const int row = blockIdx.x;
    const int tid = threadIdx.x;
    const float4 v = *(const float4*)(X + (size_t)row * 1024 + tid * 4);
    float s  = v.x + v.y + v.z + v.w;
    float s2 = v.x*v.x + v.y*v.y + v.z*v.z + v.w*v.w;
    #pragma unroll
    for (int off = 1; off < 64; off <<= 1) {
        s  += __shfl_xor(s,  off);
        s2 += __shfl_xor(s2, off);
    }
    __shared__ float rs[4], rq[4];
    if ((tid & 63) == 0) { rs[tid >> 6] = s; rq[tid >> 6] = s2; }
    __syncthreads();
    s  = rs[0] + rs[1] + rs[2] + rs[3];
    s2 = rq[0] + rq[1] + rq[2] + rq[3];
    const float mean = s * (1.f / 1024.f);
    const float var  = s2 * (1.f / 1024.f) - mean * mean;
    const float rstd = rsqrtf(var + 1e-5f);
    const float4 gv = *(const float4*)(gw + tid * 4);
    const float4 bv = *(const float4*)(bw + tid * 4);
    u16x4 o;
    o[0] = f2bf((v.x - mean) * rstd * gv.x + bv.x);
    o[1] = f2bf((v.y - mean) * rstd * gv.y + bv.y);
    o[2] = f2bf((v.z - mean) * rstd * gv.z + bv.z);
    o[3] = f2bf((v.w - mean) * rstd * gv.w + bv.w);
    *(u16x4*)(Y + (size_t)row * 1024 + tid * 4) = o;
}

// ---------------------------------------------------------------- f32 -> bf16
__global__ __launch_bounds__(256) void cast_bf16(
    const float* __restrict__ X, unsigned short* __restrict__ Y, int n4)
{
    int i = blockIdx.x * 256 + threadIdx.x;
    if (i >= n4) return;
    float4 v = ((const float4*)X)[i];
    u16x4 o = { f2bf(v.x), f2bf(v.y), f2bf(v.z), f2bf(v.w) };
    ((u16x4*)Y)[i] = o;
}

// ------------------------------------------------- W[K][N] f32 -> Wt[N][K] bf16
__global__ __launch_bounds__(256) void transpose_cast(
    const float* __restrict__ W, unsigned short* __restrict__ Wt, int K, int N)
{
    __shared__ float t[32][33];
    const int kb = blockIdx.x % (K >> 5);
    const int nb = blockIdx.x / (K >> 5);
    const int c = threadIdx.x & 31, r0 = threadIdx.x >> 5;
    #pragma unroll
    for (int i = 0; i < 4; i++)
        t[r0 + i * 8][c] = W[(size_t)(kb * 32 + r0 + i * 8) * N + nb * 32 + c];
    __syncthreads();
    #pragma unroll
    for (int i = 0; i < 4; i++)
        Wt[(size_t)(nb * 32 + r0 + i * 8) * K + kb * 32 + c] = f2bf(t[c][r0 + i * 8]);
}

// ---------------------------- four fused 1024x1024 transposes (one launch)
__global__ __launch_bounds__(256) void transpose_cast4(
    const float* __restrict__ w0, const float* __restrict__ w1,
    const float* __restrict__ w2, const float* __restrict__ w3,
    unsigned short* __restrict__ t0, unsigned short* __restrict__ t1,
    unsigned short* __restrict__ t2, unsigned short* __restrict__ t3)
{
    __shared__ float t[32][33];
    const int which = blockIdx.x >> 10;
    const float* W = which == 0 ? w0 : which == 1 ? w1 : which == 2 ? w2 : w3;
    unsigned short* Wt = which == 0 ? t0 : which == 1 ? t1 : which == 2 ? t2 : t3;
    const int idx = blockIdx.x & 1023;
    const int kb = idx & 31, nb = idx >> 5;
    const int c = threadIdx.x & 31, r0 = threadIdx.x >> 5;
    #pragma unroll
    for (int i = 0; i < 4; i++)
        t[r0 + i * 8][c] = W[(size_t)(kb * 32 + r0 + i * 8) * 1024 + nb * 32 + c];
    __syncthreads();
    #pragma unroll
    for (int i = 0; i < 4; i++)
        Wt[(size_t)(nb * 32 + r0 + i * 8) * 1024 + kb * 32 + c] = f2bf(t[c][r0 + i * 8]);
}

// --------------------------------------------- GEMM (m97 + T3 min-2-phase dbuf)
// C[m][n] = sum_k A[m][k] * Bt[n][k] + bias[n], BM=128 x BN tile, BK=32, 4 waves.
// EPI: 0 = bf16 out; 1 = V-transposed bf16 (pi-permuted k, [B*H][64][1024]);
//      2 = relu bf16; 3 = f32 out = resid + C;
//      4 = fused KV (col<1024 -> Kb linear, else Vt transposed pi-permuted)
template<int EPI, int BN>
__global__ __launch_bounds__(256) void gemm_bt(
    const unsigned short* __restrict__ A, const unsigned short* __restrict__ Bt,
    const float* __restrict__ bias, const float* __restrict__ bias2,
    void* __restrict__ outp, void* __restrict__ outp2,
    const float* __restrict__ resid, int M, int N, int K)
{
    constexpr int NF = BN / 32;                 // frags per wave in N
    constexpr int LDSH = (128 + BN) * 32;       // elems per buffer (A then B)
    __shared__ unsigned short S[2 * LDSH];      // double buffer
    const int tid = threadIdx.x;
    const int lane = tid & 63, wave = tid >> 6;
    const int g = lane >> 4, q16 = lane & 15;
    const int wm = wave >> 1, wn = wave & 1;
    const int nb = N / BN;
    const int bm = blockIdx.x / nb, bn = blockIdx.x % nb;

    const unsigned short* aSrc = A  + (size_t)(bm * 128 + (tid >> 2)) * K + (tid & 3) * 8;
    const unsigned short* bSrc = Bt + (size_t)(bn * BN  + (tid >> 2)) * K + (tid & 3) * 8;
    const size_t rowStep = (size_t)64 * K;

    f32x4 acc[4][NF] = {};

    auto STAGE = [&](int buf, int kt) {
        unsigned short* aDst = &S[buf * LDSH] + wave * 512;        // wave-uniform base
        unsigned short* bDst = &S[buf * LDSH + 4096] + wave * 512;
        __builtin_amdgcn_global_load_lds((const AS1 unsigned int*)(aSrc + kt),           (AS3 unsigned int*)aDst,          16, 0, 0);
        __builtin_amdgcn_global_load_lds((const AS1 unsigned int*)(aSrc + rowStep + kt), (AS3 unsigned int*)(aDst + 2048), 16, 0, 0);
        __builtin_amdgcn_global_load_lds((const AS1 unsigned int*)(bSrc + kt),           (AS3 unsigned int*)bDst,          16, 0, 0);
        if constexpr (BN == 128)
            __builtin_amdgcn_global_load_lds((const AS1 unsigned int*)(bSrc + rowStep + kt), (AS3 unsigned int*)(bDst + 2048), 16, 0, 0);
    };
    auto COMPUTE = [&](int buf) {
        const unsigned short* As = &S[buf * LDSH];
        const unsigned short* Bs = As + 4096;
        short8 af[4], bfr[NF];
        #pragma unroll
        for (int i = 0; i < 4; i++)  af[i]  = *(const short8*)(As + (wm * 64 + i * 16 + q16) * 32 + g * 8);
        #pragma unroll
        for (int i = 0; i < NF; i++) bfr[i] = *(const short8*)(Bs + (wn * (BN / 2) + i * 16 + q16) * 32 + g * 8);
        #pragma unroll
        for (int mf = 0; mf < 4; mf++)
            #pragma unroll
            for (int nf = 0; nf < NF; nf++)
                acc[mf][nf] = __builtin_amdgcn_mfma_f32_16x16x32_bf16(af[mf], bfr[nf], acc[mf][nf], 0, 0, 0);
    };

    STAGE(0, 0);
    __syncthreads();                 // drains vmcnt(0): buf0 ready
    int cur = 0;
    for (int kt = 32; kt < K; kt += 32) {
        STAGE(cur ^ 1, kt);          // prefetch flies under the MFMAs below
        COMPUTE(cur);
        __syncthreads();             // drain: next buf ready, cur free for overwrite
        cur ^= 1;
    }
    COMPUTE(cur);                    // last tile (no prefetch)

    const int row0 = bm * 128 + wm * 64;
    const int col0 = bn * BN + wn * (BN / 2);
    const bool isV = (EPI == 4) && (bn * BN >= 1024);   // KV-fusion: whole block uniform
    #pragma unroll
    for (int nf = 0; nf < NF; nf++) {
        const int col = col0 + nf * 16 + q16;
        const float bv = (EPI == 4 && isV) ? bias2[col - 1024] : bias[col];
        #pragma unroll
        for (int mf = 0; mf < 4; mf++) {
            const int rbase = row0 + mf * 16 + g * 4;
            #pragma unroll
            for (int r = 0; r < 4; r++) {
                const int row = rbase + r;
                const float v = acc[mf][nf][r] + bv;
                if constexpr (EPI == 0) {
                    ((unsigned short*)outp)[(size_t)row * N + col] = f2bf(v);
                } else if constexpr (EPI == 1) {
                    const int bI = row >> 10, lk = row & 1023, hh = col >> 6, dd = col & 63;
                    ((unsigned short*)outp)[((size_t)(bI * 16 + hh) * 64 + dd) * 1024 + vperm(lk)] = f2bf(v);
                } else if constexpr (EPI == 2) {
                    ((unsigned short*)outp)[(size_t)row * N + col] = f2bf(v > 0.f ? v : 0.f);
                } else if constexpr (EPI == 3) {
                    ((float*)outp)[(size_t)row * N + col] = resid[(size_t)row * N + col] + v;
                } else {  // EPI == 4: fused K/V projection, N==2048
                    if (!isV) {
                        ((unsigned short*)outp)[(size_t)row * 1024 + col] = f2bf(v);
                    } else {
                        const int cc = col - 1024;
                        const int bI = row >> 10, lk = row & 1023, hh = cc >> 6, dd = cc & 63;
                        ((unsigned short*)outp2)[((size_t)(bI * 16 + hh) * 64 + dd) * 1024 + vperm(lk)] = f2bf(v);
                    }
                }
            }
        }
    }
}

// ------------------------------------------------------------- attention PV
// Block: one (b,h) x 32 q rows; wave w owns keys [256w, 256w+256) (split-k).
// bh = blockIdx&63 so all 32 q-tiles of a (b,h) land on one XCD (L2-resident K/V).
// S^T = mfma(K,Q) leaves lane (g,q) holding keys pi(g,j); Vt is stored
// pi-permuted so the PV A-fragment is one 16B load; P stays fully in-lane.
// Epilogue: cross-wave reduction of O^T and l in LDS.
__global__ __launch_bounds__(256) void att_pv(
    const unsigned short* __restrict__ Q, const unsigned short* __restrict__ Kb,
    const unsigned short* __restrict__ Vt, unsigned short* __restrict__ O,
    float* __restrict__ LINV)
{
    __shared__ float red[4][2048];      // 32 KB partial O^T frags
    __shared__ float lred[4][2][16];
    const int tid = threadIdx.x, lane = tid & 63, wave = tid >> 6;
    const int g = lane >> 4, q16 = lane & 15;
    const int bh = blockIdx.x & 63;     // stride-64 blocks share (b,h) -> same XCD
    const int qt = blockIdx.x >> 6;
    const int b = bh >> 4, h = bh & 15;
    const int qbase = qt * 32;
    const int k0 = wave * 256;

    const unsigned short* Kp = Kb + ((size_t)b * 1024) * 1024 + h * 64;   // row stride 1024
    const unsigned short* Vp = Vt + (size_t)(bh * 64 + q16) * 1024;       // +mf*16 rows

    short8 qf[2][2];
    #pragma unroll
    for (int nf = 0; nf < 2; nf++)
        #pragma unroll
        for (int ds = 0; ds < 2; ds++)
            qf[nf][ds] = *(const short8*)(Q + (size_t)(b * 1024 + qbase + nf * 16 + q16) * 1024 + h * 64 + ds * 32 + g * 8);

    f32x4 oacc[4][2] = {};
    float lsum[2] = {0.f, 0.f};

    auto LOADK = [&](short8 (&kf)[2][2], int kc) {
        #pragma unroll
        for (int kt = 0; kt < 2; kt++)
            #pragma unroll
            for (int ds = 0; ds < 2; ds++)
                kf[kt][ds] = *(const short8*)(Kp + (size_t)(kc + kt * 16 + q16) * 1024 + ds * 32 + g * 8);
    };
    auto LOADV = [&](short8 (&vf)[4], int kc) {
        #pragma unroll
        for (int mf = 0; mf < 4; mf++)
            vf[mf] = *(const short8*)(Vp + (size_t)(mf * 16) * 1024 + kc + g * 8);  // pi-permuted
    };
    auto BODY = [&](short8 (&kf)[2][2], short8 (&vf)[4]) {
        f32x4 sacc[2][2] = {};
        #pragma unroll
        for (int kt = 0; kt < 2; kt++)
            #pragma unroll
            for (int nf = 0; nf < 2; nf++) {
                sacc[kt][nf] = __builtin_amdgcn_mfma_f32_16x16x32_bf16(kf[kt][0], qf[nf][0], sacc[kt][nf], 0, 0, 0);
                sacc[kt][nf] = __builtin_amdgcn_mfma_f32_16x16x32_bf16(kf[kt][1], qf[nf][1], sacc[kt][nf], 0, 0, 0);
            }
        float ps[2][2][4];
        #pragma unroll
        for (int kt = 0; kt < 2; kt++)
            #pragma unroll
            for (int nf = 0; nf < 2; nf++)
                #pragma unroll
                for (int r = 0; r < 4; r++)
                    ps[kt][nf][r] = __expf(sacc[kt][nf][r] * 0.125f);
        #pragma unroll
        for (int nf = 0; nf < 2; nf++) {
            float t = ps[0][nf][0] + ps[0][nf][1] + ps[0][nf][2] + ps[0][nf][3]
                    + ps[1][nf][0] + ps[1][nf][1] + ps[1][nf][2] + ps[1][nf][3];
            t += __shfl_xor(t, 16);
            t += __shfl_xor(t, 32);
            lsum[nf] += t;
        }
        short8 pbf[2];
        #pragma unroll
        for (int nf = 0; nf < 2; nf++) {
            pbf[nf][0] = (short)f2bf(ps[0][nf][0]);
            pbf[nf][1] = (short)f2bf(ps[0][nf][1]);
            pbf[nf][2] = (short)f2bf(ps[0][nf][2]);
            pbf[nf][3] = (short)f2bf(ps[0][nf][3]);
            pbf[nf][4] = (short)f2bf(ps[1][nf][0]);
            pbf[nf][5] = (short)f2bf(ps[1][nf][1]);
            pbf[nf][6] = (short)f2bf(ps[1][nf][2]);
            pbf[nf][7] = (short)f2bf(ps[1][nf][3]);
        }
        #pragma unroll
        for (int mf = 0; mf < 4; mf++)
            #pragma unroll
            for (int nf = 0; nf < 2; nf++)
                oacc[mf][nf] = __builtin_amdgcn_mfma_f32_16x16x32_bf16(vf[mf], pbf[nf], oacc[mf][nf], 0, 0, 0);
    };

    short8 kfA[2][2], kfB[2][2], vfA[4], vfB[4];
    LOADK(kfA, k0); LOADV(vfA, k0);
    for (int kc = k0; kc < k0 + 256; kc += 64) {
        LOADK(kfB, kc + 32); LOADV(vfB, kc + 32);   // prefetch flies under BODY(A)
        BODY(kfA, vfA);
        if (kc + 64 < k0 + 256) { LOADK(kfA, kc + 64); LOADV(vfA, kc + 64); }
        BODY(kfB, vfB);
    }

    // ---- cross-wave reduction (keys split over waves) ----
    #pragma unroll
    for (int mf = 0; mf < 4; mf++)
        #pragma unroll
        for (int nf = 0; nf < 2; nf++)
            *(f32x4*)&red[wave][(mf * 2 + nf) * 256 + lane * 4] = oacc[mf][nf];
    if (g == 0) { lred[wave][0][q16] = lsum[0]; lred[wave][1][q16] = lsum[1]; }
    __syncthreads();

    float lt[2];
    #pragma unroll
    for (int nf = 0; nf < 2; nf++)
        lt[nf] = lred[0][nf][q16] + lred[1][nf][q16] + lred[2][nf][q16] + lred[3][nf][q16];

    #pragma unroll
    for (int fi2 = 0; fi2 < 2; fi2++) {
        const int fi = wave * 2 + fi2;          // frag id: mf = wave, nf = fi2
        f32x4 s = *(const f32x4*)&red[0][fi * 256 + lane * 4];
        s += *(const f32x4*)&red[1][fi * 256 + lane * 4];
        s += *(const f32x4*)&red[2][fi * 256 + lane * 4];
        s += *(const f32x4*)&red[3][fi * 256 + lane * 4];
        const float inv = 1.0f / lt[fi2];
        u16x4 o;
        #pragma unroll
        for (int r = 0; r < 4; r++) o[r] = f2bf(s[r] * inv);
        *(u16x4*)(O + (size_t)(b * 1024 + qbase + fi2 * 16 + q16) * 1024 + h * 64 + wave * 16 + g * 4) = o;
    }
    if (wave == 0 && g == 0) {
        LINV[(size_t)bh * 1024 + qbase + q16]      = 1.0f / lt[0];
        LINV[(size_t)bh * 1024 + qbase + 16 + q16] = 1.0f / lt[1];
    }
}

// ------------------------------------------------- head-averaged attn output
// Block: (b, 64-q tile, 128-k tile); wave: 32 k. Loops all 16 heads,
// recomputes S with stored 1/l, accumulates mean prob, writes f32. grid=512.
__global__ __launch_bounds__(256) void att_mean(
    const unsigned short* __restrict__ Q, const unsigned short* __restrict__ Kb,
    const float* __restrict__ LINV, float* __restrict__ out1)
{
    const int tid = threadIdx.x;
    const int lane = tid & 63, wave = tid >> 6;
    const int g = lane >> 4, q16 = lane & 15;
    const int kb = blockIdx.x & 7;
    const int qb = (blockIdx.x >> 3) & 15;
    const int b = blockIdx.x >> 7;
    const int qbase = qb * 64;
    const int kbase = kb * 128 + wave * 32;

    f32x4 facc[4][2] = {};
    for (int h = 0; h < 16; h++) {
        short8 qf[4][2], kf[2][2];
        #pragma unroll
        for (int mf = 0; mf < 4; mf++)
            #pragma unroll
            for (int ds = 0; ds < 2; ds++)
                qf[mf][ds] = *(const short8*)(Q + (size_t)(b * 1024 + qbase + mf * 16 + q16) * 1024 + h * 64 + ds * 32 + g * 8);
        #pragma unroll
        for (int nf = 0; nf < 2; nf++)
            #pragma unroll
            for (int ds = 0; ds < 2; ds++)
                kf[nf][ds] = *(const short8*)(Kb + (size_t)(b * 1024 + kbase + nf * 16 + q16) * 1024 + h * 64 + ds * 32 + g * 8);
        const float* lp = LINV + (size_t)(b * 16 + h) * 1024 + qbase;
        float li[4][4];
        #pragma unroll
        for (int mf = 0; mf < 4; mf++)
            #pragma unroll
            for (int r = 0; r < 4; r++) li[mf][r] = lp[mf * 16 + g * 4 + r];
        #pragma unroll
        for (int nf = 0; nf < 2; nf++) {
            f32x4 sacc[4] = {};
            #pragma unroll
            for (int mf = 0; mf < 4; mf++) {
                sacc[mf] = __builtin_amdgcn_mfma_f32_16x16x32_bf16(qf[mf][0], kf[nf][0], sacc[mf], 0, 0, 0);
                sacc[mf] = __builtin_amdgcn_mfma_f32_16x16x32_bf16(qf[mf][1], kf[nf][1], sacc[mf], 0, 0, 0);
            }
            #pragma unroll
            for (int mf = 0; mf < 4; mf++)
                #pragma unroll
                for (int r = 0; r < 4; r++)
                    facc[mf][nf][r] += __expf(sacc[mf][r] * 0.125f) * li[mf][r];
        }
    }
    #pragma unroll
    for (int mf = 0; mf < 4; mf++)
        #pragma unroll
        for (int nf = 0; nf < 2; nf++)
            #pragma unroll
            for (int r = 0; r < 4; r++)
                out1[(size_t)(b * 1024 + qbase + mf * 16 + g * 4 + r) * 1024 + kbase + nf * 16 + q16]
                    = facc[mf][nf][r] * 0.0625f;
}

// ---------------------------------------------------------------- launcher
extern "C" void kernel_launch(void* const* d_in, const int* in_sizes, int n_in,
                              void* d_out, int out_size, void* d_ws, size_t ws_size,
                              hipStream_t stream)
{
    (void)in_sizes; (void)n_in; (void)out_size; (void)ws_size;
    const float* tgt  = (const float*)d_in[0];
    const float* mem  = (const float*)d_in[1];
    const float* ln1g = (const float*)d_in[2];
    const float* ln1b = (const float*)d_in[3];
    const float* wq   = (const float*)d_in[4];
    const float* bq   = (const float*)d_in[5];
    const float* wk   = (const float*)d_in[6];
    const float* bk   = (const float*)d_in[7];
    const float* wv   = (const float*)d_in[8];
    const float* bv   = (const float*)d_in[9];
    const float* wo   = (const float*)d_in[10];
    const float* bo   = (const float*)d_in[11];
    const float* ln3g = (const float*)d_in[12];
    const float* ln3b = (const float*)d_in[13];
    const float* w1   = (const float*)d_in[14];
    const float* b1   = (const float*)d_in[15];
    const float* w2   = (const float*)d_in[16];
    const float* b2   = (const float*)d_in[17];

    char* ws = (char*)d_ws;
    unsigned short* XA  = (unsigned short*)(ws);                  // 8 MB (t2, later t3)
    unsigned short* M16 = (unsigned short*)(ws + ((size_t)8  << 20));
    unsigned short* WQT = (unsigned short*)(ws + ((size_t)16 << 20));
    unsigned short* WKT = (unsigned short*)(ws + ((size_t)18 << 20)); // [WKT;WVT] = fused 2048xK
    unsigned short* WVT = (unsigned short*)(ws + ((size_t)20 << 20));
    unsigned short* WOT = (unsigned short*)(ws + ((size_t)22 << 20));
    unsigned short* W1T = (unsigned short*)(ws + ((size_t)24 << 20)); // 8 MB
    unsigned short* W2T = (unsigned short*)(ws + ((size_t)32 << 20)); // 8 MB
    unsigned short* Qb  = (unsigned short*)(ws + ((size_t)40 << 20));
    unsigned short* Kb  = (unsigned short*)(ws + ((size_t)48 << 20));
    unsigned short* Vt  = (unsigned short*)(ws + ((size_t)56 << 20));
    unsigned short* O16 = (unsigned short*)(ws + ((size_t)64 << 20));
    unsigned short* H16 = (unsigned short*)(ws + ((size_t)72 << 20)); // 32 MB
    float*          LNV = (float*)(ws + ((size_t)104 << 20));         // 256 KB
    float* xout = (float*)d_out;                       // x then x+ffn [4096][1024]
    float* attn = xout + (size_t)4 * 1024 * 1024;      // [4][1024][1024]

    ln_to_bf16<<<4096, 256, 0, stream>>>(tgt, ln1g, ln1b, XA);
    cast_bf16<<<4096, 256, 0, stream>>>(mem, M16, 1024 * 1024);
    transpose_cast4<<<4096, 256, 0, stream>>>(wq, wk, wv, wo, WQT, WKT, WVT, WOT);
    transpose_cast<<<32 * 128, 256, 0, stream>>>(w1, W1T, 1024, 4096);
    transpose_cast<<<128 * 32, 256, 0, stream>>>(w2, W2T, 4096, 1024);

    // Q projection: N=1024, BN=64 -> grid 512 (2 blocks/CU)
    gemm_bt<0, 64><<<32 * 16, 256, 0, stream>>>(XA, WQT, bq, nullptr, Qb, nullptr, nullptr, 4096, 1024, 1024);
    // fused K+V projection: N=2048, BN=128 -> grid 512
    gemm_bt<4, 128><<<32 * 16, 256, 0, stream>>>(M16, WKT, bk, bv, Kb, Vt, nullptr, 4096, 2048, 1024);

    att_pv<<<2048, 256, 0, stream>>>(Qb, Kb, Vt, O16, LNV);
    att_mean<<<512, 256, 0, stream>>>(Qb, Kb, LNV, attn);

    // WO: N=1024, BN=64 -> grid 512
    gemm_bt<3, 64><<<32 * 16, 256, 0, stream>>>(O16, WOT, bo, nullptr, xout, nullptr, tgt, 4096, 1024, 1024);
    ln_to_bf16<<<4096, 256, 0, stream>>>(xout, ln3g, ln3b, XA);
    // FFN1: N=4096, BN=128 -> grid 1024
    gemm_bt<2, 128><<<32 * 32, 256, 0, stream>>>(XA, W1T, b1, nullptr, H16, nullptr, nullptr, 4096, 4096, 1024);
    // FFN2: N=1024, K=4096, BN=64 -> grid 512
    gemm_bt<3, 64><<<32 * 16, 256, 0, stream>>>(H16, W2T, b2, nullptr, xout, nullptr, xout, 4096, 1024, 4096);
}

// Round 6
// 343.992 us; speedup vs baseline: 1.0907x; 1.0179x over previous
//
#include <hip/hip_runtime.h>
#include <hip/hip_bf16.h>

using short8 = __attribute__((ext_vector_type(8))) short;          // 8 bf16 (4 VGPR)
using f32x4  = __attribute__((ext_vector_type(4))) float;          // MFMA acc
using u16x4  = __attribute__((ext_vector_type(4))) unsigned short; // 8B bf16 store

#define AS1 __attribute__((address_space(1)))
#define AS3 __attribute__((address_space(3)))

__device__ __forceinline__ unsigned short f2bf(float f) {
    __hip_bfloat16 h = __float2bfloat16(f);    // RNE; compiler can pair into v_cvt_pk_bf16_f32
    return __builtin_bit_cast(unsigned short, h);
}

__device__ __forceinline__ float exp2_hw(float x) {
    float r;
    asm("v_exp_f32 %0, %1" : "=v"(r) : "v"(x));   // D = 2^S0, 1 trans op
    return r;
}

// pi-permutation of key k within a 32-key chunk: position of key k in the
// slot order {4g..4g+3, 16+4g..19+4g} for g = 0..3 (slot = g*8+j).
__device__ __forceinline__ int vperm(int lk) {
    return (lk & ~31) | (((lk >> 2) & 3) * 8) | (((lk >> 4) & 1) * 4) | (lk & 3);
}

// ---------------------------------------------------------------- LN -> bf16
__global__ __launch_bounds__(256) void ln_to_bf16(
    const float* __restrict__ X, const float* __restrict__ gw,
    const float* __restrict__ bw, unsigned short* __restrict__ Y)
{
    const int row = blockIdx.x;
    const int tid = threadIdx.x;
    const float4 v = *(const float4*)(X + (size_t)row * 1024 + tid * 4);
    float s  = v.x + v.y + v.z + v.w;
    float s2 = v.x*v.x + v.y*v.y + v.z*v.z + v.w*v.w;
    #pragma unroll
    for (int off = 1; off < 64; off <<= 1) {
        s  += __shfl_xor(s,  off);
        s2 += __shfl_xor(s2, off);
    }
    __shared__ float rs[4], rq[4];
    if ((tid & 63) == 0) { rs[tid >> 6] = s; rq[tid >> 6] = s2; }
    __syncthreads();
    s  = rs[0] + rs[1] + rs[2] + rs[3];
    s2 = rq[0] + rq[1] + rq[2] + rq[3];
    const float mean = s * (1.f / 1024.f);
    const float var  = s2 * (1.f / 1024.f) - mean * mean;
    const float rstd = rsqrtf(var + 1e-5f);
    const float4 gv = *(const float4*)(gw + tid * 4);
    const float4 bv = *(const float4*)(bw + tid * 4);
    u16x4 o;
    o[0] = f2bf((v.x - mean) * rstd * gv.x + bv.x);
    o[1] = f2bf((v.y - mean) * rstd * gv.y + bv.y);
    o[2] = f2bf((v.z - mean) * rstd * gv.z + bv.z);
    o[3] = f2bf((v.w - mean) * rstd * gv.w + bv.w);
    *(u16x4*)(Y + (size_t)row * 1024 + tid * 4) = o;
}

// ---------------------------------------------------------------- f32 -> bf16
__global__ __launch_bounds__(256) void cast_bf16(
    const float* __restrict__ X, unsigned short* __restrict__ Y, int n4)
{
    int i = blockIdx.x * 256 + threadIdx.x;
    if (i >= n4) return;
    float4 v = ((const float4*)X)[i];
    u16x4 o = { f2bf(v.x), f2bf(v.y), f2bf(v.z), f2bf(v.w) };
    ((u16x4*)Y)[i] = o;
}

// ------------------------------------------------- W[K][N] f32 -> Wt[N][K] bf16
__global__ __launch_bounds__(256) void transpose_cast(
    const float* __restrict__ W, unsigned short* __restrict__ Wt, int K, int N)
{
    __shared__ float t[32][33];
    const int kb = blockIdx.x % (K >> 5);
    const int nb = blockIdx.x / (K >> 5);
    const int c = threadIdx.x & 31, r0 = threadIdx.x >> 5;
    #pragma unroll
    for (int i = 0; i < 4; i++)
        t[r0 + i * 8][c] = W[(size_t)(kb * 32 + r0 + i * 8) * N + nb * 32 + c];
    __syncthreads();
    #pragma unroll
    for (int i = 0; i < 4; i++)
        Wt[(size_t)(nb * 32 + r0 + i * 8) * K + kb * 32 + c] = f2bf(t[c][r0 + i * 8]);
}

// ---------------------------- four fused 1024x1024 transposes (one launch)
__global__ __launch_bounds__(256) void transpose_cast4(
    const float* __restrict__ w0, const float* __restrict__ w1,
    const float* __restrict__ w2, const float* __restrict__ w3,
    unsigned short* __restrict__ t0, unsigned short* __restrict__ t1,
    unsigned short* __restrict__ t2, unsigned short* __restrict__ t3)
{
    __shared__ float t[32][33];
    const int which = blockIdx.x >> 10;
    const float* W = which == 0 ? w0 : which == 1 ? w1 : which == 2 ? w2 : w3;
    unsigned short* Wt = which == 0 ? t0 : which == 1 ? t1 : which == 2 ? t2 : t3;
    const int idx = blockIdx.x & 1023;
    const int kb = idx & 31, nb = idx >> 5;
    const int c = threadIdx.x & 31, r0 = threadIdx.x >> 5;
    #pragma unroll
    for (int i = 0; i < 4; i++)
        t[r0 + i * 8][c] = W[(size_t)(kb * 32 + r0 + i * 8) * 1024 + nb * 32 + c];
    __syncthreads();
    #pragma unroll
    for (int i = 0; i < 4; i++)
        Wt[(size_t)(nb * 32 + r0 + i * 8) * 1024 + kb * 32 + c] = f2bf(t[c][r0 + i * 8]);
}

// ------------------------------------- GEMM (m97 + T3 dbuf, PF-deep staging)
// C[m][n] = sum_k A[m][k] * Bt[n][k] + bias[n], BM=128 x BN tile, 4 waves.
// PF = 32-k sub-tiles staged per phase (ring of 2*PF LDS slots, 1 barrier/phase).
// EPI: 0 = bf16 out scaled by oscale; 1 = V-transposed bf16 (pi-permuted);
//      2 = relu bf16; 3 = f32 out = resid + C;
//      4 = fused KV (col<1024 -> Kb linear, else Vt transposed pi-permuted)
template<int EPI, int BN, int PF>
__global__ __launch_bounds__(256) void gemm_bt(
    const unsigned short* __restrict__ A, const unsigned short* __restrict__ Bt,
    const float* __restrict__ bias, const float* __restrict__ bias2,
    void* __restrict__ outp, void* __restrict__ outp2,
    const float* __restrict__ resid, float oscale, int M, int N, int K)
{
    constexpr int NF = BN / 32;                 // frags per wave in N
    constexpr int LDSH = (128 + BN) * 32;       // elems per 32-k slot (A then B)
    __shared__ unsigned short S[2 * PF * LDSH]; // slot ring
    const int tid = threadIdx.x;
    const int lane = tid & 63, wave = tid >> 6;
    const int g = lane >> 4, q16 = lane & 15;
    const int wm = wave >> 1, wn = wave & 1;
    const int nb = N / BN;
    const int bm = blockIdx.x / nb, bn = blockIdx.x % nb;

    const unsigned short* aSrc = A  + (size_t)(bm * 128 + (tid >> 2)) * K + (tid & 3) * 8;
    const unsigned short* bSrc = Bt + (size_t)(bn * BN  + (tid >> 2)) * K + (tid & 3) * 8;
    const size_t rowStep = (size_t)64 * K;

    f32x4 acc[4][NF] = {};

    auto STAGE = [&](int slot, int kt) {
        unsigned short* aDst = &S[slot * LDSH] + wave * 512;       // wave-uniform base
        unsigned short* bDst = &S[slot * LDSH + 4096] + wave * 512;
        __builtin_amdgcn_global_load_lds((const AS1 unsigned int*)(aSrc + kt),           (AS3 unsigned int*)aDst,          16, 0, 0);
        __builtin_amdgcn_global_load_lds((const AS1 unsigned int*)(aSrc + rowStep + kt), (AS3 unsigned int*)(aDst + 2048), 16, 0, 0);
        __builtin_amdgcn_global_load_lds((const AS1 unsigned int*)(bSrc + kt),           (AS3 unsigned int*)bDst,          16, 0, 0);
        if constexpr (BN == 128)
            __builtin_amdgcn_global_load_lds((const AS1 unsigned int*)(bSrc + rowStep + kt), (AS3 unsigned int*)(bDst + 2048), 16, 0, 0);
    };
    auto COMPUTE = [&](int slot) {
        const unsigned short* As = &S[slot * LDSH];
        const unsigned short* Bs = As + 4096;
        short8 af[4], bfr[NF];
        #pragma unroll
        for (int i = 0; i < 4; i++)  af[i]  = *(const short8*)(As + (wm * 64 + i * 16 + q16) * 32 + g * 8);
        #pragma unroll
        for (int i = 0; i < NF; i++) bfr[i] = *(const short8*)(Bs + (wn * (BN / 2) + i * 16 + q16) * 32 + g * 8);
        #pragma unroll
        for (int mf = 0; mf < 4; mf++)
            #pragma unroll
            for (int nf = 0; nf < NF; nf++)
                acc[mf][nf] = __builtin_amdgcn_mfma_f32_16x16x32_bf16(af[mf], bfr[nf], acc[mf][nf], 0, 0, 0);
    };

    #pragma unroll
    for (int i = 0; i < PF; i++) STAGE(i, i * 32);
    __syncthreads();                 // drain: slots [0,PF) ready
    int p = 0;
    for (int kt = PF * 32; kt < K; kt += PF * 32) {
        #pragma unroll
        for (int i = 0; i < PF; i++) STAGE((p ^ 1) * PF + i, kt + i * 32);  // prefetch pair
        #pragma unroll
        for (int i = 0; i < PF; i++) COMPUTE(p * PF + i);
        __syncthreads();             // next slots ready; current free for overwrite
        p ^= 1;
    }
    #pragma unroll
    for (int i = 0; i < PF; i++) COMPUTE(p * PF + i);   // tail (no prefetch)

    const int row0 = bm * 128 + wm * 64;
    const int col0 = bn * BN + wn * (BN / 2);
    const bool isV = (EPI == 4) && (bn * BN >= 1024);   // KV-fusion: whole block uniform
    #pragma unroll
    for (int nf = 0; nf < NF; nf++) {
        const int col = col0 + nf * 16 + q16;
        const float bv = (EPI == 4 && isV) ? bias2[col - 1024] : bias[col];
        #pragma unroll
        for (int mf = 0; mf < 4; mf++) {
            const int rbase = row0 + mf * 16 + g * 4;
            #pragma unroll
            for (int r = 0; r < 4; r++) {
                const int row = rbase + r;
                const float v = acc[mf][nf][r] + bv;
                if constexpr (EPI == 0) {
                    ((unsigned short*)outp)[(size_t)row * N + col] = f2bf(v * oscale);
                } else if constexpr (EPI == 1) {
                    const int bI = row >> 10, lk = row & 1023, hh = col >> 6, dd = col & 63;
                    ((unsigned short*)outp)[((size_t)(bI * 16 + hh) * 64 + dd) * 1024 + vperm(lk)] = f2bf(v);
                } else if constexpr (EPI == 2) {
                    ((unsigned short*)outp)[(size_t)row * N + col] = f2bf(v > 0.f ? v : 0.f);
                } else if constexpr (EPI == 3) {
                    ((float*)outp)[(size_t)row * N + col] = resid[(size_t)row * N + col] + v;
                } else {  // EPI == 4: fused K/V projection, N==2048
                    if (!isV) {
                        ((unsigned short*)outp)[(size_t)row * 1024 + col] = f2bf(v);
                    } else {
                        const int cc = col - 1024;
                        const int bI = row >> 10, lk = row & 1023, hh = cc >> 6, dd = cc & 63;
                        ((unsigned short*)outp2)[((size_t)(bI * 16 + hh) * 64 + dd) * 1024 + vperm(lk)] = f2bf(v);
                    }
                }
            }
        }
    }
}

// ------------------------------------------------------------- attention PV
// Block: one (b,h) x 32 q rows; wave w owns keys [256w, 256w+256) (split-k).
// bh = blockIdx&63 so all 32 q-tiles of a (b,h) land on one XCD (L2-resident K/V).
// Q is PRESCALED by 0.125*log2(e) at projection: P = exp2(sacc), no muls.
// S^T = mfma(K,Q) leaves lane (g,q) holding keys pi(g,j); Vt is stored
// pi-permuted so the PV A-fragment is one 16B load; P stays fully in-lane.
// lsum cross-lane reduce deferred to after the k-loop (sum is linear).
__global__ __launch_bounds__(256) void att_pv(
    const unsigned short* __restrict__ Q, const unsigned short* __restrict__ Kb,
    const unsigned short* __restrict__ Vt, unsigned short* __restrict__ O,
    float* __restrict__ LINV)
{
    __shared__ float red[4][2048];      // 32 KB partial O^T frags
    __shared__ float lred[4][2][16];
    const int tid = threadIdx.x, lane = tid & 63, wave = tid >> 6;
    const int g = lane >> 4, q16 = lane & 15;
    const int bh = blockIdx.x & 63;     // stride-64 blocks share (b,h) -> same XCD
    const int qt = blockIdx.x >> 6;
    const int b = bh >> 4, h = bh & 15;
    const int qbase = qt * 32;
    const int k0 = wave * 256;

    const unsigned short* Kp = Kb + ((size_t)b * 1024) * 1024 + h * 64;   // row stride 1024
    const unsigned short* Vp = Vt + (size_t)(bh * 64 + q16) * 1024;       // +mf*16 rows

    short8 qf[2][2];
    #pragma unroll
    for (int nf = 0; nf < 2; nf++)
        #pragma unroll
        for (int ds = 0; ds < 2; ds++)
            qf[nf][ds] = *(const short8*)(Q + (size_t)(b * 1024 + qbase + nf * 16 + q16) * 1024 + h * 64 + ds * 32 + g * 8);

    f32x4 oacc[4][2] = {};
    float lsum[2] = {0.f, 0.f};

    auto LOADK = [&](short8 (&kf)[2][2], int kc) {
        #pragma unroll
        for (int kt = 0; kt < 2; kt++)
            #pragma unroll
            for (int ds = 0; ds < 2; ds++)
                kf[kt][ds] = *(const short8*)(Kp + (size_t)(kc + kt * 16 + q16) * 1024 + ds * 32 + g * 8);
    };
    auto LOADV = [&](short8 (&vf)[4], int kc) {
        #pragma unroll
        for (int mf = 0; mf < 4; mf++)
            vf[mf] = *(const short8*)(Vp + (size_t)(mf * 16) * 1024 + kc + g * 8);  // pi-permuted
    };
    auto BODY = [&](short8 (&kf)[2][2], short8 (&vf)[4]) {
        f32x4 sacc[2][2] = {};
        #pragma unroll
        for (int kt = 0; kt < 2; kt++)
            #pragma unroll
            for (int nf = 0; nf < 2; nf++) {
                sacc[kt][nf] = __builtin_amdgcn_mfma_f32_16x16x32_bf16(kf[kt][0], qf[nf][0], sacc[kt][nf], 0, 0, 0);
                sacc[kt][nf] = __builtin_amdgcn_mfma_f32_16x16x32_bf16(kf[kt][1], qf[nf][1], sacc[kt][nf], 0, 0, 0);
            }
        float ps[2][2][4];
        #pragma unroll
        for (int kt = 0; kt < 2; kt++)
            #pragma unroll
            for (int nf = 0; nf < 2; nf++)
                #pragma unroll
                for (int r = 0; r < 4; r++)
                    ps[kt][nf][r] = exp2_hw(sacc[kt][nf][r]);
        #pragma unroll
        for (int nf = 0; nf < 2; nf++)
            lsum[nf] += ps[0][nf][0] + ps[0][nf][1] + ps[0][nf][2] + ps[0][nf][3]
                      + ps[1][nf][0] + ps[1][nf][1] + ps[1][nf][2] + ps[1][nf][3];
        short8 pbf[2];
        #pragma unroll
        for (int nf = 0; nf < 2; nf++) {
            pbf[nf][0] = (short)f2bf(ps[0][nf][0]);
            pbf[nf][1] = (short)f2bf(ps[0][nf][1]);
            pbf[nf][2] = (short)f2bf(ps[0][nf][2]);
            pbf[nf][3] = (short)f2bf(ps[0][nf][3]);
            pbf[nf][4] = (short)f2bf(ps[1][nf][0]);
            pbf[nf][5] = (short)f2bf(ps[1][nf][1]);
            pbf[nf][6] = (short)f2bf(ps[1][nf][2]);
            pbf[nf][7] = (short)f2bf(ps[1][nf][3]);
        }
        #pragma unroll
        for (int mf = 0; mf < 4; mf++)
            #pragma unroll
            for (int nf = 0; nf < 2; nf++)
                oacc[mf][nf] = __builtin_amdgcn_mfma_f32_16x16x32_bf16(vf[mf], pbf[nf], oacc[mf][nf], 0, 0, 0);
    };

    short8 kfA[2][2], kfB[2][2], vfA[4], vfB[4];
    LOADK(kfA, k0); LOADV(vfA, k0);
    for (int kc = k0; kc < k0 + 256; kc += 64) {
        LOADK(kfB, kc + 32); LOADV(vfB, kc + 32);   // prefetch flies under BODY(A)
        BODY(kfA, vfA);
        if (kc + 64 < k0 + 256) { LOADK(kfA, kc + 64); LOADV(vfA, kc + 64); }
        BODY(kfB, vfB);
    }
    #pragma unroll
    for (int nf = 0; nf < 2; nf++) {               // deferred cross-lane reduce
        lsum[nf] += __shfl_xor(lsum[nf], 16);
        lsum[nf] += __shfl_xor(lsum[nf], 32);
    }

    // ---- cross-wave reduction (keys split over waves) ----
    #pragma unroll
    for (int mf = 0; mf < 4; mf++)
        #pragma unroll
        for (int nf = 0; nf < 2; nf++)
            *(f32x4*)&red[wave][(mf * 2 + nf) * 256 + lane * 4] = oacc[mf][nf];
    if (g == 0) { lred[wave][0][q16] = lsum[0]; lred[wave][1][q16] = lsum[1]; }
    __syncthreads();

    float lt[2];
    #pragma unroll
    for (int nf = 0; nf < 2; nf++)
        lt[nf] = lred[0][nf][q16] + lred[1][nf][q16] + lred[2][nf][q16] + lred[3][nf][q16];

    #pragma unroll
    for (int fi2 = 0; fi2 < 2; fi2++) {
        const int fi = wave * 2 + fi2;          // frag id: mf = wave, nf = fi2
        f32x4 s = *(const f32x4*)&red[0][fi * 256 + lane * 4];
        s += *(const f32x4*)&red[1][fi * 256 + lane * 4];
        s += *(const f32x4*)&red[2][fi * 256 + lane * 4];
        s += *(const f32x4*)&red[3][fi * 256 + lane * 4];
        const float inv = 1.0f / lt[fi2];
        u16x4 o;
        #pragma unroll
        for (int r = 0; r < 4; r++) o[r] = f2bf(s[r] * inv);
        *(u16x4*)(O + (size_t)(b * 1024 + qbase + fi2 * 16 + q16) * 1024 + h * 64 + wave * 16 + g * 4) = o;
    }
    if (wave == 0 && g == 0) {
        LINV[(size_t)bh * 1024 + qbase + q16]      = 1.0f / lt[0];
        LINV[(size_t)bh * 1024 + qbase + 16 + q16] = 1.0f / lt[1];
    }
}

// ------------------------------------------------- head-averaged attn output
// Block: (b, 32-q tile, 128-k tile); wave: 32 k. Loops all 16 heads,
// recomputes S (prescaled Q -> exp2) with stored 1/l, writes f32. grid=1024.
__global__ __launch_bounds__(256) void att_mean(
    const unsigned short* __restrict__ Q, const unsigned short* __restrict__ Kb,
    const float* __restrict__ LINV, float* __restrict__ out1)
{
    const int tid = threadIdx.x;
    const int lane = tid & 63, wave = tid >> 6;
    const int g = lane >> 4, q16 = lane & 15;
    const int kb = blockIdx.x & 7;
    const int qb = (blockIdx.x >> 3) & 31;
    const int b = blockIdx.x >> 8;
    const int qbase = qb * 32;
    const int kbase = kb * 128 + wave * 32;

    f32x4 facc[2][2] = {};
    for (int h = 0; h < 16; h++) {
        short8 qf[2][2], kf[2][2];
        #pragma unroll
        for (int mf = 0; mf < 2; mf++)
            #pragma unroll
            for (int ds = 0; ds < 2; ds++)
                qf[mf][ds] = *(const short8*)(Q + (size_t)(b * 1024 + qbase + mf * 16 + q16) * 1024 + h * 64 + ds * 32 + g * 8);
        #pragma unroll
        for (int nf = 0; nf < 2; nf++)
            #pragma unroll
            for (int ds = 0; ds < 2; ds++)
                kf[nf][ds] = *(const short8*)(Kb + (size_t)(b * 1024 + kbase + nf * 16 + q16) * 1024 + h * 64 + ds * 32 + g * 8);
        const float* lp = LINV + (size_t)(b * 16 + h) * 1024 + qbase;
        float li[2][4];
        #pragma unroll
        for (int mf = 0; mf < 2; mf++)
            #pragma unroll
            for (int r = 0; r < 4; r++) li[mf][r] = lp[mf * 16 + g * 4 + r];
        #pragma unroll
        for (int nf = 0; nf < 2; nf++) {
            f32x4 sacc[2] = {};
            #pragma unroll
            for (int mf = 0; mf < 2; mf++) {
                sacc[mf] = __builtin_amdgcn_mfma_f32_16x16x32_bf16(qf[mf][0], kf[nf][0], sacc[mf], 0, 0, 0);
                sacc[mf] = __builtin_amdgcn_mfma_f32_16x16x32_bf16(qf[mf][1], kf[nf][1], sacc[mf], 0, 0, 0);
            }
            #pragma unroll
            for (int mf = 0; mf < 2; mf++)
                #pragma unroll
                for (int r = 0; r < 4; r++)
                    facc[mf][nf][r] = fmaf(exp2_hw(sacc[mf][r]), li[mf][r], facc[mf][nf][r]);
        }
    }
    #pragma unroll
    for (int mf = 0; mf < 2; mf++)
        #pragma unroll
        for (int nf = 0; nf < 2; nf++)
            #pragma unroll
            for (int r = 0; r < 4; r++)
                out1[(size_t)(b * 1024 + qbase + mf * 16 + g * 4 + r) * 1024 + kbase + nf * 16 + q16]
                    = facc[mf][nf][r] * 0.0625f;
}

// ---------------------------------------------------------------- launcher
extern "C" void kernel_launch(void* const* d_in, const int* in_sizes, int n_in,
                              void* d_out, int out_size, void* d_ws, size_t ws_size,
                              hipStream_t stream)
{
    (void)in_sizes; (void)n_in; (void)out_size; (void)ws_size;
    const float* tgt  = (const float*)d_in[0];
    const float* mem  = (const float*)d_in[1];
    const float* ln1g = (const float*)d_in[2];
    const float* ln1b = (const float*)d_in[3];
    const float* wq   = (const float*)d_in[4];
    const float* bq   = (const float*)d_in[5];
    const float* wk   = (const float*)d_in[6];
    const float* bk   = (const float*)d_in[7];
    const float* wv   = (const float*)d_in[8];
    const float* bv   = (const float*)d_in[9];
    const float* wo   = (const float*)d_in[10];
    const float* bo   = (const float*)d_in[11];
    const float* ln3g = (const float*)d_in[12];
    const float* ln3b = (const float*)d_in[13];
    const float* w1   = (const float*)d_in[14];
    const float* b1   = (const float*)d_in[15];
    const float* w2   = (const float*)d_in[16];
    const float* b2   = (const float*)d_in[17];

    char* ws = (char*)d_ws;
    unsigned short* XA  = (unsigned short*)(ws);                  // 8 MB (t2, later t3)
    unsigned short* M16 = (unsigned short*)(ws + ((size_t)8  << 20));
    unsigned short* WQT = (unsigned short*)(ws + ((size_t)16 << 20));
    unsigned short* WKT = (unsigned short*)(ws + ((size_t)18 << 20)); // [WKT;WVT] = fused 2048xK
    unsigned short* WVT = (unsigned short*)(ws + ((size_t)20 << 20));
    unsigned short* WOT = (unsigned short*)(ws + ((size_t)22 << 20));
    unsigned short* W1T = (unsigned short*)(ws + ((size_t)24 << 20)); // 8 MB
    unsigned short* W2T = (unsigned short*)(ws + ((size_t)32 << 20)); // 8 MB
    unsigned short* Qb  = (unsigned short*)(ws + ((size_t)40 << 20));
    unsigned short* Kb  = (unsigned short*)(ws + ((size_t)48 << 20));
    unsigned short* Vt  = (unsigned short*)(ws + ((size_t)56 << 20));
    unsigned short* O16 = (unsigned short*)(ws + ((size_t)64 << 20));
    unsigned short* H16 = (unsigned short*)(ws + ((size_t)72 << 20)); // 32 MB
    float*          LNV = (float*)(ws + ((size_t)104 << 20));         // 256 KB
    float* xout = (float*)d_out;                       // x then x+ffn [4096][1024]
    float* attn = xout + (size_t)4 * 1024 * 1024;      // [4][1024][1024]

    const float QSCALE = 0.125f * 1.4426950408889634f;   // fold softmax scale + log2e into Q

    ln_to_bf16<<<4096, 256, 0, stream>>>(tgt, ln1g, ln1b, XA);
    cast_bf16<<<4096, 256, 0, stream>>>(mem, M16, 1024 * 1024);
    transpose_cast4<<<4096, 256, 0, stream>>>(wq, wk, wv, wo, WQT, WKT, WVT, WOT);
    transpose_cast<<<32 * 128, 256, 0, stream>>>(w1, W1T, 1024, 4096);
    transpose_cast<<<128 * 32, 256, 0, stream>>>(w2, W2T, 4096, 1024);

    // Q projection (prescaled): N=1024, BN=64, PF=2 -> grid 512
    gemm_bt<0, 64, 2><<<32 * 16, 256, 0, stream>>>(XA, WQT, bq, nullptr, Qb, nullptr, nullptr, QSCALE, 4096, 1024, 1024);
    // fused K+V projection: N=2048, BN=128 -> grid 512
    gemm_bt<4, 128, 1><<<32 * 16, 256, 0, stream>>>(M16, WKT, bk, bv, Kb, Vt, nullptr, 1.0f, 4096, 2048, 1024);

    att_pv<<<2048, 256, 0, stream>>>(Qb, Kb, Vt, O16, LNV);
    att_mean<<<1024, 256, 0, stream>>>(Qb, Kb, LNV, attn);

    // WO: N=1024, BN=64, PF=2 -> grid 512
    gemm_bt<3, 64, 2><<<32 * 16, 256, 0, stream>>>(O16, WOT, bo, nullptr, xout, nullptr, tgt, 1.0f, 4096, 1024, 1024);
    ln_to_bf16<<<4096, 256, 0, stream>>>(xout, ln3g, ln3b, XA);
    // FFN1: N=4096, BN=128 -> grid 1024
    gemm_bt<2, 128, 1><<<32 * 32, 256, 0, stream>>>(XA, W1T, b1, nullptr, H16, nullptr, nullptr, 1.0f, 4096, 4096, 1024);
    // FFN2: N=1024, K=4096, BN=64, PF=2 -> grid 512
    gemm_bt<3, 64, 2><<<32 * 16, 256, 0, stream>>>(H16, W2T, b2, nullptr, xout, nullptr, xout, 1.0f, 4096, 1024, 4096);
}